// Round 7
// baseline (809.985 us; speedup 1.0000x reference)
//
#include <hip/hip_runtime.h>

#define N_TOT 400000
#define NELEM (N_TOT * 16)
#define NREG  128
#define RCAP  8192
#define SACC      262144.0f        // conv fixed-point scale 2^18
#define INV_SACC  (1.0f / 262144.0f)

typedef __attribute__((ext_vector_type(8))) short short8;
typedef __attribute__((ext_vector_type(4))) float f32x4;

__device__ __forceinline__ unsigned short f2bf(float x) {
    unsigned int u = __float_as_uint(x);
    u += 0x7FFFu + ((u >> 16) & 1u);       // round-to-nearest-even
    return (unsigned short)(u >> 16);
}
__device__ __forceinline__ float bf2f(unsigned short h) {
    return __uint_as_float(((unsigned int)h) << 16);
}

// ---- once-per-launch kernels -------------------------------------------------

__global__ __launch_bounds__(128) void zero_k(int* cnt) {
    if (threadIdx.x < NREG) cnt[threadIdx.x] = 0;
}

// Compact valid non-center (k,voxel) pairs into 128 regions.
// Entry: (out_v | k<<19, in_v). Wave-aggregated atomic region counters.
// List ORDER is nondeterministic; downstream int accumulation commutes exactly,
// so final output is bitwise deterministic.
__global__ __launch_bounds__(256) void build_k(const int* __restrict__ nbr,
                                               int* __restrict__ cnt,
                                               int2* __restrict__ pairs) {
    int v  = blockIdx.x * 256 + threadIdx.x;
    int ks = blockIdx.y;                    // 0..25
    int k  = ks < 13 ? ks : ks + 1;         // skip center
    int in_v = -1;
    if (v < N_TOT) in_v = nbr[(size_t)k * N_TOT + v];
    bool valid = in_v >= 0;
    unsigned long long m = __ballot(valid);
    if (m == 0ull) return;
    int lane = threadIdx.x & 63;
    int r = (blockIdx.x + blockIdx.y * 1563) & (NREG - 1);
    int n = __popcll(m);
    int leader = __ffsll((unsigned long long)m) - 1;
    int base = 0;
    if (lane == leader) base = atomicAdd(&cnt[r], n);
    base = __shfl(base, leader);
    if (valid) {
        int pos = base + __popcll(m & ((1ull << lane) - 1ull));
        if (pos < RCAP)
            pairs[(size_t)r * RCAP + pos] = make_int2(v | (k << 19), in_v);
    }
}

// Weight prep: (a) wsp[L][k][cq][ci][cj] bf16 for the sparse pass,
// (b) wctr[L][lane][8] center B-fragments for mfma_f32_16x16x32_bf16
//     (lane l holds B[k=8*(l>>4)+j][col=l&15]; klocal>=16 -> 0).
__global__ __launch_bounds__(256) void prep_k(const float* __restrict__ w_in,
                                              const float* __restrict__ wbs,
                                              unsigned short* __restrict__ wsp,
                                              unsigned short* __restrict__ wctr) {
    int t = blockIdx.x * 256 + threadIdx.x;
    if (t < 5 * 27 * 256) {
        int L = t / 6912, rem = t % 6912;
        int k = rem / 256, r2 = rem % 256;
        int ci = r2 / 16, c = r2 % 16;
        float w = (L == 0) ? w_in[(k * 16 + ci) * 16 + c]
                           : wbs[((L - 1) * 27 + k) * 256 + ci * 16 + c];
        int dst = ((k * 4 + (c >> 2)) * 16 + ci) * 4 + (c & 3);
        wsp[L * 6912 + dst] = f2bf(w);
    } else if (t < 5 * 27 * 256 + 5 * 512) {
        int u = t - 5 * 27 * 256;
        int L = u / 512, rem = u % 512;
        int lane = rem / 8, j = rem % 8;
        int g = lane >> 4, col = lane & 15;
        int kl = 8 * g + j;
        float w = 0.f;
        if (g < 2) w = (L == 0) ? w_in[(13 * 16 + kl) * 16 + col]
                                : wbs[((L - 1) * 27 + 13) * 256 + kl * 16 + col];
        wctr[u] = f2bf(w);
    }
}

__global__ __launch_bounds__(256) void cvt_k(const float* __restrict__ in,
                                             unsigned short* __restrict__ out) {
    int i = (blockIdx.x * 256 + threadIdx.x) * 8;
    f32x4 a = *reinterpret_cast<const f32x4*>(in + i);
    f32x4 b = *reinterpret_cast<const f32x4*>(in + i + 4);
    short8 o = { (short)f2bf(a[0]), (short)f2bf(a[1]), (short)f2bf(a[2]), (short)f2bf(a[3]),
                 (short)f2bf(b[0]), (short)f2bf(b[1]), (short)f2bf(b[2]), (short)f2bf(b[3]) };
    *reinterpret_cast<short8*>(out + i) = o;
}

// ---- per-layer kernels -------------------------------------------------------

// Dense center pass (k=13 identity): one MFMA per 16-voxel tile, plain int32
// stores (initializes the accumulator). Block 0 also zeroes the S8 shadows.
__global__ __launch_bounds__(256) void center_k(const unsigned short* __restrict__ feats,
                                                const unsigned short* __restrict__ wctr,
                                                int* __restrict__ oi,
                                                unsigned long long* __restrict__ S8) {
    if (blockIdx.x == 0) S8[threadIdx.x] = 0ull;   // 8*32 = 256 entries
    const int lane = threadIdx.x & 63;
    const int wv   = threadIdx.x >> 6;
    const int vv   = (blockIdx.x * 4 + wv) * 16;
    const int g    = lane >> 4, rc = lane & 15;
    short8 b = *reinterpret_cast<const short8*>(wctr + lane * 8);
    short8 a = {0, 0, 0, 0, 0, 0, 0, 0};
    if (g < 2) a = *reinterpret_cast<const short8*>(feats + (size_t)(vv + rc) * 16 + 8 * g);
    f32x4 acc = {0.f, 0.f, 0.f, 0.f};
    acc = __builtin_amdgcn_mfma_f32_16x16x32_bf16(a, b, acc, 0, 0, 0);
#pragma unroll
    for (int i = 0; i < 4; ++i)
        oi[(size_t)(vv + g * 4 + i) * 16 + rc] = __float2int_rn(acc[i] * SACC);
}

// Sparse pass: 4 lanes per pair (4 output channels each). LDS bf16 weights,
// 32B feature gather, 64 FMA, 4 int32 atomicAdds (exact-commutative).
__global__ __launch_bounds__(256) void sparse_k(const unsigned short* __restrict__ feats,
                                                const unsigned short* __restrict__ wsp,
                                                const int2* __restrict__ pairs,
                                                const int* __restrict__ cnt,
                                                int* __restrict__ oi) {
    __shared__ unsigned short wlds[6912];
    {
        const f32x4* src = reinterpret_cast<const f32x4*>(wsp);
        f32x4* dst = reinterpret_cast<f32x4*>(wlds);
        for (int j = threadIdx.x; j < 864; j += 256) dst[j] = src[j];
    }
    __syncthreads();
    const int lane = threadIdx.x & 63;
    const int w  = blockIdx.x * 4 + (threadIdx.x >> 6);  // 0..4095
    const int r  = w & (NREG - 1);
    const int lw = w >> 7;                               // 0..31
    const int cq = lane & 3;
    int cr = min(cnt[r], RCAP);
    const int2* pr = pairs + (size_t)r * RCAP;
    for (int pb = lw * 16; pb < cr; pb += 32 * 16) {
        int pi = pb + (lane >> 2);
        if (pi < cr) {
            int2 e = pr[pi];
            int out_v = e.x & 0x7FFFF;
            int k     = e.x >> 19;
            int in_v  = e.y;
            short8 x0 = *reinterpret_cast<const short8*>(feats + (size_t)in_v * 16);
            short8 x1 = *reinterpret_cast<const short8*>(feats + (size_t)in_v * 16 + 8);
            float xf[16];
#pragma unroll
            for (int j = 0; j < 8; ++j) {
                xf[j]     = bf2f((unsigned short)x0[j]);
                xf[8 + j] = bf2f((unsigned short)x1[j]);
            }
            float a0 = 0.f, a1 = 0.f, a2 = 0.f, a3 = 0.f;
            const unsigned short* wb = wlds + ((k * 4 + cq) * 16) * 4;
#pragma unroll
            for (int ii = 0; ii < 8; ++ii) {
                short8 w8 = *reinterpret_cast<const short8*>(wb + ii * 8);
                float xlo = xf[2 * ii], xhi = xf[2 * ii + 1];
                a0 += xlo * bf2f((unsigned short)w8[0]) + xhi * bf2f((unsigned short)w8[4]);
                a1 += xlo * bf2f((unsigned short)w8[1]) + xhi * bf2f((unsigned short)w8[5]);
                a2 += xlo * bf2f((unsigned short)w8[2]) + xhi * bf2f((unsigned short)w8[6]);
                a3 += xlo * bf2f((unsigned short)w8[3]) + xhi * bf2f((unsigned short)w8[7]);
            }
            int* ob = oi + (size_t)out_v * 16 + cq * 4;
            atomicAdd(ob + 0, __float2int_rn(a0 * SACC));
            atomicAdd(ob + 1, __float2int_rn(a1 * SACC));
            atomicAdd(ob + 2, __float2int_rn(a2 * SACC));
            atomicAdd(ob + 3, __float2int_rn(a3 * SACC));
        }
    }
}

// BN sums: fixed-order f32 partials per block, scaled-int64 atomics into
// 8 shadow copies (exact, deterministic). 800 blocks x 256.
__global__ __launch_bounds__(256) void reduce_k(const int* __restrict__ oi,
                                                unsigned long long* __restrict__ S8) {
    int gtid = blockIdx.x * 256 + threadIdx.x;
    float s = 0.f, q = 0.f;
    for (size_t e = (size_t)gtid; e < (size_t)NELEM; e += 204800) {
        float f = (float)oi[e] * INV_SACC;
        s += f; q += f * f;
    }
    __shared__ float sa[256], qa[256];
    sa[threadIdx.x] = s; qa[threadIdx.x] = q;
    __syncthreads();
    if (threadIdx.x < 32) {
        int c = threadIdx.x & 15;
        bool isq = threadIdx.x >= 16;
        float acc = 0.f;
#pragma unroll
        for (int j = 0; j < 16; ++j) acc += (isq ? qa : sa)[c + 16 * j];
        long long v = llrintf(acc * (isq ? 16384.0f : 65536.0f));
        atomicAdd(&S8[(blockIdx.x & 7) * 32 + threadIdx.x], (unsigned long long)v);
    }
}

// BN finalize + ReLU + optional residual; reads int32 conv accumulator,
// writes bf16 features and/or f32 final output. Sums the 8 S8 shadows inline.
__global__ __launch_bounds__(256) void apply_k(const int* __restrict__ oi,
                                               const unsigned long long* __restrict__ S8,
                                               const float* __restrict__ gamma,
                                               const float* __restrict__ beta,
                                               const unsigned short* residb,
                                               unsigned short* bfout,
                                               float* f32out) {
    __shared__ float scs[16], shs[16];
    if (threadIdx.x < 16) {
        int c = threadIdx.x;
        long long ss = 0, qq = 0;
#pragma unroll
        for (int j = 0; j < 8; ++j) {
            ss += (long long)S8[j * 32 + c];
            qq += (long long)S8[j * 32 + 16 + c];
        }
        float s = (float)ss * (1.0f / 65536.0f);
        float q = (float)qq * (1.0f / 16384.0f);
        const float invN = 1.0f / (float)N_TOT;
        float m   = s * invN;
        float var = q * invN - m * m;
        float sc  = gamma[c] * rsqrtf(var + 1e-3f);
        scs[c] = sc;
        shs[c] = beta[c] - m * sc;
    }
    __syncthreads();
    int gtid = blockIdx.x * 256 + threadIdx.x;
    int c0 = (gtid & 1) * 8;
    for (size_t e = (size_t)gtid * 8; e < (size_t)NELEM; e += 204800ull * 8) {
        int4 a = *reinterpret_cast<const int4*>(oi + e);
        int4 b = *reinterpret_cast<const int4*>(oi + e + 4);
        float res[8] = {0, 0, 0, 0, 0, 0, 0, 0};
        if (residb) {
            short8 r8 = *reinterpret_cast<const short8*>(residb + e);
#pragma unroll
            for (int j = 0; j < 8; ++j) res[j] = bf2f((unsigned short)r8[j]);
        }
        int av[8] = {a.x, a.y, a.z, a.w, b.x, b.y, b.z, b.w};
        float v[8];
#pragma unroll
        for (int j = 0; j < 8; ++j)
            v[j] = fmaxf((float)av[j] * INV_SACC * scs[c0 + j] + shs[c0 + j] + res[j], 0.f);
        if (bfout) {
            short8 o = { (short)f2bf(v[0]), (short)f2bf(v[1]), (short)f2bf(v[2]), (short)f2bf(v[3]),
                         (short)f2bf(v[4]), (short)f2bf(v[5]), (short)f2bf(v[6]), (short)f2bf(v[7]) };
            *reinterpret_cast<short8*>(bfout + e) = o;
        }
        if (f32out) {
            f32x4 lo = { v[0], v[1], v[2], v[3] };
            f32x4 hi = { v[4], v[5], v[6], v[7] };
            *reinterpret_cast<f32x4*>(f32out + e)     = lo;
            *reinterpret_cast<f32x4*>(f32out + e + 4) = hi;
        }
    }
}

extern "C" void kernel_launch(void* const* d_in, const int* in_sizes, int n_in,
                              void* d_out, int out_size, void* d_ws, size_t ws_size,
                              hipStream_t stream) {
    const float* vf   = (const float*)d_in[0];
    const int*   nbr  = (const int*)  d_in[1];
    const float* w_in = (const float*)d_in[2];
    const float* g_in = (const float*)d_in[3];
    const float* b_in = (const float*)d_in[4];
    const float* wbs  = (const float*)d_in[5];
    const float* gs   = (const float*)d_in[6];
    const float* bs   = (const float*)d_in[7];
    float* out = (float*)d_out;

    char* ws = (char*)d_ws;
    size_t off = 0;
    auto alloc = [&](size_t b) { char* p = ws + off; off += (b + 255) & ~(size_t)255; return p; };
    unsigned short*     wsp   = (unsigned short*)alloc((size_t)5 * 27 * 256 * 2);
    unsigned short*     wctr  = (unsigned short*)alloc((size_t)5 * 512 * 2);
    unsigned short*     xb    = (unsigned short*)alloc((size_t)NELEM * 2);
    unsigned short*     ob    = (unsigned short*)alloc((size_t)NELEM * 2);
    int*                oi    = (int*)alloc((size_t)NELEM * 4);
    int2*               pairs = (int2*)alloc((size_t)NREG * RCAP * 8);
    int*                cnt   = (int*)alloc(NREG * 4);
    unsigned long long* S8    = (unsigned long long*)alloc(8 * 32 * 8);

    zero_k<<<1, 128, 0, stream>>>(cnt);
    build_k<<<dim3(1563, 26), 256, 0, stream>>>(nbr, cnt, pairs);
    prep_k<<<145, 256, 0, stream>>>(w_in, wbs, wsp, wctr);
    cvt_k<<<3125, 256, 0, stream>>>(vf, xb);

    struct Lay { const unsigned short* in; const float *g, *b;
                 const unsigned short* resid; unsigned short* bfo; float* f32o; };
    Lay lays[5] = {
        { xb, g_in,    b_in,    nullptr, xb, nullptr },   // L0: x0
        { xb, gs + 0,  bs + 0,  nullptr, ob, nullptr },   // L1: o
        { ob, gs + 16, bs + 16, xb,      xb, nullptr },   // L2: x1 (+x0)
        { xb, gs + 32, bs + 32, nullptr, ob, nullptr },   // L3: o
        { ob, gs + 48, bs + 48, xb,      nullptr, out },  // L4: out (+x1)
    };
    for (int L = 0; L < 5; ++L) {
        center_k<<<6250, 256, 0, stream>>>(lays[L].in, wctr + L * 512, oi, S8);
        sparse_k<<<1024, 256, 0, stream>>>(lays[L].in, wsp + L * 6912, pairs, cnt, oi);
        reduce_k<<<800, 256, 0, stream>>>(oi, S8);
        apply_k<<<800, 256, 0, stream>>>(oi, S8, lays[L].g, lays[L].b,
                                         lays[L].resid, lays[L].bfo, lays[L].f32o);
    }
}

// Round 8
// 448.726 us; speedup vs baseline: 1.8051x; 1.8051x over previous
//
#include <hip/hip_runtime.h>

#define N_TOT  400000
#define NTILE  25000        // N_TOT / 16 voxels per tile
#define NELEM  (N_TOT * 16)
#define CBLK   512          // persistent conv blocks (2 per CU)
#define GS     (CBLK * 4)   // wave grid stride (tiles)

typedef __attribute__((ext_vector_type(8))) short short8;
typedef __attribute__((ext_vector_type(4))) float f32x4;

__device__ __forceinline__ unsigned short f2bf(float x) {
    unsigned int u = __float_as_uint(x);
    u += 0x7FFFu + ((u >> 16) & 1u);       // round-to-nearest-even
    return (unsigned short)(u >> 16);
}
__device__ __forceinline__ float bf2f(unsigned short h) {
    return __uint_as_float(((unsigned int)h) << 16);
}

// Build bf16 B-fragments for all 5 layers x 14 k-pairs.
// mfma_f32_16x16x32_bf16 B layout: lane l holds B[k=8*(l>>4)+j][col=l&15].
__global__ __launch_bounds__(64) void wfrag_k(const float* __restrict__ w_in,
                                              const float* __restrict__ wbs,
                                              unsigned short* __restrict__ wfrag) {
    int b = blockIdx.x;            // L*14 + p
    int L = b / 14, p = b % 14;
    int l = threadIdx.x;
    int g = l >> 4, col = l & 15;
    int k = 2 * p + (g >> 1);
    int cib = (g & 1) * 8;
    unsigned short v[8];
#pragma unroll
    for (int j = 0; j < 8; ++j) {
        float w = 0.f;
        if (k < 27) {
            int ci = cib + j;
            w = (L == 0) ? w_in[(k * 16 + ci) * 16 + col]
                         : wbs[(((L - 1) * 27 + k) * 16 + ci) * 16 + col];
        }
        v[j] = f2bf(w);
    }
    unsigned short* dst = wfrag + (size_t)(b * 64 + l) * 8;
#pragma unroll
    for (int j = 0; j < 8; ++j) dst[j] = v[j];
}

__global__ __launch_bounds__(256) void cvt_k(const float* __restrict__ in,
                                             unsigned short* __restrict__ out) {
    int i = (blockIdx.x * 256 + threadIdx.x) * 8;
    f32x4 a = *reinterpret_cast<const f32x4*>(in + i);
    f32x4 b = *reinterpret_cast<const f32x4*>(in + i + 4);
    short8 o = { (short)f2bf(a[0]), (short)f2bf(a[1]), (short)f2bf(a[2]), (short)f2bf(a[3]),
                 (short)f2bf(b[0]), (short)f2bf(b[1]), (short)f2bf(b[2]), (short)f2bf(b[3]) };
    *reinterpret_cast<short8*>(out + i) = o;
}

// Once per launch: validity descriptors. dsc[t*14+p] bit (ksel*16+rc) = 1 iff
// offset k=2p+ksel is valid for voxel t*16+rc. k==13 (center) bits always set.
// One wave per tile; ballot -> plain store (NO atomics).
__global__ __launch_bounds__(256) void desc_k(const int* __restrict__ nbr,
                                              unsigned int* __restrict__ dsc) {
    const int lane = threadIdx.x & 63;
    const int wv   = threadIdx.x >> 6;
    const int t    = blockIdx.x * 4 + wv;
    const int g    = lane >> 4;
    const int rc   = lane & 15;
    const int ksel = g >> 1;
    const int vv   = t * 16;
#pragma unroll
    for (int p = 0; p < 14; ++p) {
        int k = 2 * p + ksel;
        bool valid;
        if (k == 13)     valid = true;
        else if (k < 27) valid = nbr[(size_t)k * N_TOT + vv + rc] >= 0;
        else             valid = false;
        unsigned long long b = __ballot(valid);
        unsigned int mask = (unsigned int)(b & 0xFFFFull) |
                            ((unsigned int)(b >> 16) & 0xFFFF0000u);
        if (lane == 0) dsc[(size_t)t * 14 + p] = mask;
    }
}

// Persistent gather-MFMA conv, 3-stage decoupled pipeline per wave:
//   idx loads (desc-masked) tile t+2S | gathers (lane-masked) t+S | MFMA t.
// Empty pairs (no valid lane) skip their ds_read+MFMA via a wave-uniform
// branch on NE (14-bit nonempty mask from ballots). No atomics, no zero voxel.
#define IDX(I, tt)                                                              \
  {                                                                             \
    const int vv = (tt) * 16;                                                   \
    const unsigned int* dp = dsc + (size_t)(tt) * 14;                           \
    _Pragma("unroll")                                                           \
    for (int p = 0; p < 14; ++p) {                                              \
      int k = 2 * p + ksel;                                                     \
      int id = -1;                                                              \
      if (k == 13) id = vv + rc;                                                \
      else if (k < 27) {                                                        \
        unsigned int d = dp[p];                                                 \
        if ((d >> bit) & 1u) id = nbr[(size_t)k * N_TOT + vv + rc];             \
      }                                                                         \
      I[p] = id;                                                                \
    }                                                                           \
  }

#define GAT(A, NE, I)                                                           \
  {                                                                             \
    NE = 0;                                                                     \
    _Pragma("unroll")                                                           \
    for (int p = 0; p < 14; ++p) {                                              \
      short8 z = {0, 0, 0, 0, 0, 0, 0, 0};                                      \
      A[p] = z;                                                                 \
      bool vld = I[p] >= 0;                                                     \
      if (vld)                                                                  \
        A[p] = *reinterpret_cast<const short8*>(feats + ((size_t)I[p] << 4) + half); \
      if (__ballot(vld) != 0ull) NE |= (1 << p);                                \
    }                                                                           \
  }

#define CMP(A, NE, tt)                                                          \
  {                                                                             \
    f32x4 acc = {0.f, 0.f, 0.f, 0.f};                                           \
    _Pragma("unroll")                                                           \
    for (int p = 0; p < 14; ++p) {                                              \
      if (__builtin_amdgcn_readfirstlane((NE >> p) & 1)) {                      \
        short8 bf = *reinterpret_cast<const short8*>(&wlds[(p * 64 + lane) * 8]); \
        acc = __builtin_amdgcn_mfma_f32_16x16x32_bf16(A[p], bf, acc, 0, 0, 0);  \
      }                                                                         \
    }                                                                           \
    const int vv = (tt) * 16;                                                   \
    _Pragma("unroll")                                                           \
    for (int i = 0; i < 4; ++i)                                                 \
      raw[(size_t)(vv + g * 4 + i) * 16 + rc] = f2bf(acc[i]);                   \
    s_acc += acc[0] + acc[1] + acc[2] + acc[3];                                 \
    q_acc += acc[0]*acc[0] + acc[1]*acc[1] + acc[2]*acc[2] + acc[3]*acc[3];     \
  }

__global__ __launch_bounds__(256, 2) void conv_k(const unsigned short* __restrict__ feats,
                                                 const int* __restrict__ nbr,
                                                 const unsigned int* __restrict__ dsc,
                                                 const unsigned short* __restrict__ wfrag,
                                                 unsigned short* __restrict__ raw,
                                                 float* __restrict__ partials) {
    __shared__ unsigned short wlds[14 * 64 * 8];   // 14336 B
    __shared__ float red[128];

    {   // cooperative wfrag stage: 14336 B = 896 x 16 B (once per block)
        const f32x4* src = reinterpret_cast<const f32x4*>(wfrag);
        f32x4* dst = reinterpret_cast<f32x4*>(wlds);
        for (int j = threadIdx.x; j < 896; j += 256) dst[j] = src[j];
    }
    __syncthreads();

    const int lane = threadIdx.x & 63;
    const int wv   = threadIdx.x >> 6;
    const int g    = lane >> 4;
    const int rc   = lane & 15;        // A-row / B-col
    const int half = (g & 1) * 8;      // which 8 input channels this lane loads
    const int ksel = g >> 1;           // which offset of the pair
    const int bit  = ksel * 16 + rc;   // this lane's desc bit

    float s_acc = 0.f, q_acc = 0.f;

    int I0[14], I1[14];
    short8 A0[14], A1[14];
    int ne0 = 0, ne1 = 0;

    int t0 = blockIdx.x * 4 + wv;
    IDX(I0, t0);
    GAT(A0, ne0, I0);                  // one exposed stall at prologue
    int t1 = t0 + GS;
    if (t1 < NTILE) IDX(I1, t1);

    for (;;) {
        int t2 = t0 + 2 * GS;
        if (t2 < NTILE) IDX(I0, t2);
        if (t1 < NTILE) GAT(A1, ne1, I1);
        __builtin_amdgcn_sched_barrier(0);
        CMP(A0, ne0, t0);
        if (t1 >= NTILE) break;

        int t3 = t1 + 2 * GS;
        if (t3 < NTILE) IDX(I1, t3);
        if (t2 < NTILE) GAT(A0, ne0, I0);
        __builtin_amdgcn_sched_barrier(0);
        CMP(A1, ne1, t1);
        if (t2 >= NTILE) break;

        t0 = t2;
        t1 = t2 + GS;
    }

    // BN partials: per-channel sum & sumsq over all tiles this block touched
    s_acc += __shfl_xor(s_acc, 16);  s_acc += __shfl_xor(s_acc, 32);
    q_acc += __shfl_xor(q_acc, 16);  q_acc += __shfl_xor(q_acc, 32);
    if (lane < 16) {
        red[wv * 32 + rc]      = s_acc;
        red[wv * 32 + 16 + rc] = q_acc;
    }
    __syncthreads();
    if (threadIdx.x < 32) {
        float v = red[threadIdx.x] + red[32 + threadIdx.x] +
                  red[64 + threadIdx.x] + red[96 + threadIdx.x];
        partials[(size_t)threadIdx.x * CBLK + blockIdx.x] = v;
    }
}

__global__ __launch_bounds__(256) void reduce_k(const float* __restrict__ partials,
                                                float* __restrict__ S) {
    int c = blockIdx.x;  // 0..31 (16 sums, 16 sumsqs)
    float s = 0.f;
    for (int i = threadIdx.x; i < CBLK; i += 256) s += partials[(size_t)c * CBLK + i];
    __shared__ float red[256];
    red[threadIdx.x] = s;
    __syncthreads();
#pragma unroll
    for (int off = 128; off > 0; off >>= 1) {
        if (threadIdx.x < off) red[threadIdx.x] += red[threadIdx.x + off];
        __syncthreads();
    }
    if (threadIdx.x == 0) S[c] = red[0];
}

// BN finalize fused; reads raw bf16 conv output, optional bf16 residual,
// writes bf16 feature buffer and/or f32 final output. 8 elems/thread.
__global__ __launch_bounds__(256) void apply_k(const unsigned short* __restrict__ raw,
                                               const float* __restrict__ S,
                                               const float* __restrict__ gamma,
                                               const float* __restrict__ beta,
                                               const unsigned short* residb,
                                               unsigned short* bfout,
                                               float* f32out) {
    int i = (blockIdx.x * 256 + threadIdx.x) * 8;
    int c0 = i & 8;                    // channels c0..c0+7
    short8 r8 = *reinterpret_cast<const short8*>(raw + i);
    float res[8] = {0, 0, 0, 0, 0, 0, 0, 0};
    if (residb) {
        short8 x8 = *reinterpret_cast<const short8*>(residb + i);
#pragma unroll
        for (int j = 0; j < 8; ++j) res[j] = bf2f((unsigned short)x8[j]);
    }
    const float inv = 1.0f / (float)N_TOT;
    float val[8];
#pragma unroll
    for (int j = 0; j < 8; ++j) {
        int c = c0 + j;
        float m   = S[c] * inv;
        float var = S[16 + c] * inv - m * m;
        float sc  = gamma[c] * rsqrtf(var + 1e-3f);
        float sh  = beta[c] - m * sc;
        val[j] = fmaxf(bf2f((unsigned short)r8[j]) * sc + sh + res[j], 0.f);
    }
    if (bfout) {
        short8 o = { (short)f2bf(val[0]), (short)f2bf(val[1]), (short)f2bf(val[2]), (short)f2bf(val[3]),
                     (short)f2bf(val[4]), (short)f2bf(val[5]), (short)f2bf(val[6]), (short)f2bf(val[7]) };
        *reinterpret_cast<short8*>(bfout + i) = o;
    }
    if (f32out) {
        f32x4 lo = { val[0], val[1], val[2], val[3] };
        f32x4 hi = { val[4], val[5], val[6], val[7] };
        *reinterpret_cast<f32x4*>(f32out + i)     = lo;
        *reinterpret_cast<f32x4*>(f32out + i + 4) = hi;
    }
}

extern "C" void kernel_launch(void* const* d_in, const int* in_sizes, int n_in,
                              void* d_out, int out_size, void* d_ws, size_t ws_size,
                              hipStream_t stream) {
    const float* vf   = (const float*)d_in[0];
    const int*   nbr  = (const int*)  d_in[1];
    const float* w_in = (const float*)d_in[2];
    const float* g_in = (const float*)d_in[3];
    const float* b_in = (const float*)d_in[4];
    const float* wbs  = (const float*)d_in[5];
    const float* gs   = (const float*)d_in[6];
    const float* bs   = (const float*)d_in[7];
    float* out = (float*)d_out;

    char* ws = (char*)d_ws;
    size_t off = 0;
    auto alloc = [&](size_t b) { char* p = ws + off; off += (b + 255) & ~(size_t)255; return p; };
    unsigned short* wfrag = (unsigned short*)alloc((size_t)5 * 14 * 64 * 8 * 2);
    unsigned short* xb    = (unsigned short*)alloc((size_t)NELEM * 2);  // bf16 features (x)
    unsigned short* ob    = (unsigned short*)alloc((size_t)NELEM * 2);  // bf16 features (o)
    unsigned short* rb    = (unsigned short*)alloc((size_t)NELEM * 2);  // bf16 raw conv out
    unsigned int*   dsc   = (unsigned int*)alloc((size_t)NTILE * 14 * 4);
    float*          part  = (float*)alloc((size_t)32 * CBLK * 4);
    float*          S     = (float*)alloc(32 * 4);

    const int FR = 14 * 64 * 8;  // ushorts per layer of wfrag

    wfrag_k<<<70, 64, 0, stream>>>(w_in, wbs, wfrag);
    cvt_k<<<3125, 256, 0, stream>>>(vf, xb);
    desc_k<<<6250, 256, 0, stream>>>(nbr, dsc);

    // L0: x0 = relu(bn(conv(vf)))                 -> xb
    conv_k<<<CBLK, 256, 0, stream>>>(xb, nbr, dsc, wfrag, rb, part);
    reduce_k<<<32, 256, 0, stream>>>(part, S);
    apply_k<<<3125, 256, 0, stream>>>(rb, S, g_in, b_in, nullptr, xb, nullptr);

    // L1: o = relu(bn(conv(x0)))                  -> ob
    conv_k<<<CBLK, 256, 0, stream>>>(xb, nbr, dsc, wfrag + FR, rb, part);
    reduce_k<<<32, 256, 0, stream>>>(part, S);
    apply_k<<<3125, 256, 0, stream>>>(rb, S, gs + 0, bs + 0, nullptr, ob, nullptr);

    // L2: x1 = relu(bn(conv(o)) + x0)             -> xb (in place resid)
    conv_k<<<CBLK, 256, 0, stream>>>(ob, nbr, dsc, wfrag + 2 * FR, rb, part);
    reduce_k<<<32, 256, 0, stream>>>(part, S);
    apply_k<<<3125, 256, 0, stream>>>(rb, S, gs + 16, bs + 16, xb, xb, nullptr);

    // L3: o = relu(bn(conv(x1)))                  -> ob
    conv_k<<<CBLK, 256, 0, stream>>>(xb, nbr, dsc, wfrag + 3 * FR, rb, part);
    reduce_k<<<32, 256, 0, stream>>>(part, S);
    apply_k<<<3125, 256, 0, stream>>>(rb, S, gs + 32, bs + 32, nullptr, ob, nullptr);

    // L4: out = relu(bn(conv(o)) + x1)            -> d_out (f32)
    conv_k<<<CBLK, 256, 0, stream>>>(ob, nbr, dsc, wfrag + 4 * FR, rb, part);
    reduce_k<<<32, 256, 0, stream>>>(part, S);
    apply_k<<<3125, 256, 0, stream>>>(rb, S, gs + 48, bs + 48, xb, nullptr, out);
}

// Round 9
// 309.023 us; speedup vs baseline: 2.6211x; 1.4521x over previous
//
#include <hip/hip_runtime.h>

#define N_TOT  400000
#define NTILE  25000        // N_TOT / 16 voxels per tile
#define NELEM  (N_TOT * 16)
#define CBLK   768          // persistent conv blocks (3 per CU)
#define GS     (CBLK * 4)   // wave grid stride (tiles)

typedef __attribute__((ext_vector_type(8))) short short8;
typedef __attribute__((ext_vector_type(4))) float f32x4;
typedef __attribute__((ext_vector_type(4))) unsigned short us4;

__device__ __forceinline__ unsigned short f2bf(float x) {
    unsigned int u = __float_as_uint(x);
    u += 0x7FFFu + ((u >> 16) & 1u);       // round-to-nearest-even
    return (unsigned short)(u >> 16);
}
__device__ __forceinline__ float bf2f(unsigned short h) {
    return __uint_as_float(((unsigned int)h) << 16);
}

// Build bf16 B-fragments for all 5 layers x 14 k-pairs, and zero the pad voxel
// (index N_TOT) in both bf16 gather buffers (invalid neighbors land there —
// all invalid lanes hit the SAME cache line, coalesced to one broadcast).
// mfma_f32_16x16x32_bf16 B layout: lane l holds B[k=8*(l>>4)+j][col=l&15].
__global__ __launch_bounds__(64) void wfrag_k(const float* __restrict__ w_in,
                                              const float* __restrict__ wbs,
                                              unsigned short* __restrict__ wfrag,
                                              unsigned short* __restrict__ xb,
                                              unsigned short* __restrict__ ob) {
    if (blockIdx.x == 0 && threadIdx.x < 8) {
        us4 z = {0, 0, 0, 0};
        unsigned short* base = (threadIdx.x < 4) ? xb : ob;
        reinterpret_cast<us4*>(base + NELEM)[threadIdx.x & 3] = z;
    }
    int b = blockIdx.x;            // L*14 + p
    int L = b / 14, p = b % 14;
    int l = threadIdx.x;
    int g = l >> 4, col = l & 15;
    int k = 2 * p + (g >> 1);
    int cib = (g & 1) * 8;
    unsigned short v[8];
#pragma unroll
    for (int j = 0; j < 8; ++j) {
        float w = 0.f;
        if (k < 27) {
            int ci = cib + j;
            w = (L == 0) ? w_in[(k * 16 + ci) * 16 + col]
                         : wbs[(((L - 1) * 27 + k) * 16 + ci) * 16 + col];
        }
        v[j] = f2bf(w);
    }
    unsigned short* dst = wfrag + (size_t)(b * 64 + l) * 8;
#pragma unroll
    for (int j = 0; j < 8; ++j) dst[j] = v[j];
}

__global__ __launch_bounds__(256) void cvt_k(const float* __restrict__ in,
                                             unsigned short* __restrict__ out) {
    int i = (blockIdx.x * 256 + threadIdx.x) * 8;
    f32x4 a = *reinterpret_cast<const f32x4*>(in + i);
    f32x4 b = *reinterpret_cast<const f32x4*>(in + i + 4);
    short8 o = { (short)f2bf(a[0]), (short)f2bf(a[1]), (short)f2bf(a[2]), (short)f2bf(a[3]),
                 (short)f2bf(b[0]), (short)f2bf(b[1]), (short)f2bf(b[2]), (short)f2bf(b[3]) };
    *reinterpret_cast<short8*>(out + i) = o;
}

// Persistent gather-MFMA conv, 3-stage decoupled pipeline per wave:
//   idx loads for tile t+2S | gathers for tile t+S | MFMA+store of tile t.
// Straight-line, branch-free lane work (cndmask only). wfrag in LDS per block.
// Center offset (k=13) = identity (no load). Invalid -> zero voxel at N_TOT.
#define IDX(I, tt)                                                              \
  {                                                                             \
    const int vv = (tt) * 16;                                                   \
    _Pragma("unroll")                                                           \
    for (int p = 0; p < 14; ++p) {                                              \
      int k = 2 * p + ksel;                                                     \
      if (k == 13)      I[p] = vv + rc;                                         \
      else if (k < 27)  I[p] = nbr[(size_t)k * N_TOT + vv + rc];                \
      else              I[p] = -1;                                              \
    }                                                                           \
  }

#define GAT(A, I)                                                               \
  {                                                                             \
    _Pragma("unroll")                                                           \
    for (int p = 0; p < 14; ++p) {                                              \
      int ci = I[p] < 0 ? N_TOT : I[p];                                         \
      A[p] = *reinterpret_cast<const short8*>(feats + ((size_t)ci << 4) + half);\
    }                                                                           \
  }

#define CMP(A, tt)                                                              \
  {                                                                             \
    f32x4 acc = {0.f, 0.f, 0.f, 0.f};                                           \
    _Pragma("unroll")                                                           \
    for (int p = 0; p < 14; ++p) {                                              \
      short8 bf = *reinterpret_cast<const short8*>(&wlds[(p * 64 + lane) * 8]); \
      acc = __builtin_amdgcn_mfma_f32_16x16x32_bf16(A[p], bf, acc, 0, 0, 0);    \
    }                                                                           \
    const int vv = (tt) * 16;                                                   \
    _Pragma("unroll")                                                           \
    for (int i = 0; i < 4; ++i)                                                 \
      raw[(size_t)(vv + g * 4 + i) * 16 + rc] = f2bf(acc[i]);                   \
    s_acc += acc[0] + acc[1] + acc[2] + acc[3];                                 \
    q_acc += acc[0]*acc[0] + acc[1]*acc[1] + acc[2]*acc[2] + acc[3]*acc[3];     \
  }

__global__ __launch_bounds__(256, 3) void conv_k(const unsigned short* __restrict__ feats,
                                                 const int* __restrict__ nbr,
                                                 const unsigned short* __restrict__ wfrag,
                                                 unsigned short* __restrict__ raw,
                                                 float* __restrict__ partials) {
    __shared__ unsigned short wlds[14 * 64 * 8];   // 14336 B
    __shared__ float red[128];

    {   // cooperative wfrag stage: 14336 B = 896 x 16 B (once per block)
        const f32x4* src = reinterpret_cast<const f32x4*>(wfrag);
        f32x4* dst = reinterpret_cast<f32x4*>(wlds);
        for (int j = threadIdx.x; j < 896; j += 256) dst[j] = src[j];
    }
    __syncthreads();

    const int lane = threadIdx.x & 63;
    const int wv   = threadIdx.x >> 6;
    const int g    = lane >> 4;
    const int rc   = lane & 15;        // A-row / B-col
    const int half = (g & 1) * 8;      // which 8 input channels this lane loads
    const int ksel = g >> 1;           // which offset of the pair

    float s_acc = 0.f, q_acc = 0.f;

    int I0[14], I1[14];
    short8 A0[14], A1[14];

    int t0 = blockIdx.x * 4 + wv;
    IDX(I0, t0);
    GAT(A0, I0);                       // one exposed stall at prologue
    int t1 = t0 + GS;
    if (t1 < NTILE) IDX(I1, t1);

    for (;;) {
        // invariant: A0 in flight for t0; I1 in flight/arrived for t1
        int t2 = t0 + 2 * GS;
        if (t2 < NTILE) IDX(I0, t2);
        if (t1 < NTILE) GAT(A1, I1);
        __builtin_amdgcn_sched_barrier(0);
        CMP(A0, t0);
        if (t1 >= NTILE) break;

        int t3 = t1 + 2 * GS;
        if (t3 < NTILE) IDX(I1, t3);
        if (t2 < NTILE) GAT(A0, I0);
        __builtin_amdgcn_sched_barrier(0);
        CMP(A1, t1);
        if (t2 >= NTILE) break;

        t0 = t2;
        t1 = t2 + GS;
    }

    // BN partials: per-channel sum & sumsq over all tiles this block touched
    s_acc += __shfl_xor(s_acc, 16);  s_acc += __shfl_xor(s_acc, 32);
    q_acc += __shfl_xor(q_acc, 16);  q_acc += __shfl_xor(q_acc, 32);
    if (lane < 16) {
        red[wv * 32 + rc]      = s_acc;
        red[wv * 32 + 16 + rc] = q_acc;
    }
    __syncthreads();
    if (threadIdx.x < 32) {
        float v = red[threadIdx.x] + red[32 + threadIdx.x] +
                  red[64 + threadIdx.x] + red[96 + threadIdx.x];
        partials[(size_t)threadIdx.x * CBLK + blockIdx.x] = v;
    }
}

__global__ __launch_bounds__(256) void reduce_k(const float* __restrict__ partials,
                                                float* __restrict__ S) {
    int c = blockIdx.x;  // 0..31 (16 sums, 16 sumsqs)
    float s = 0.f;
    for (int i = threadIdx.x; i < CBLK; i += 256) s += partials[(size_t)c * CBLK + i];
    __shared__ float red[256];
    red[threadIdx.x] = s;
    __syncthreads();
#pragma unroll
    for (int off = 128; off > 0; off >>= 1) {
        if (threadIdx.x < off) red[threadIdx.x] += red[threadIdx.x + off];
        __syncthreads();
    }
    if (threadIdx.x == 0) S[c] = red[0];
}

// BN finalize fused; reads raw bf16 conv output, optional bf16 residual,
// writes bf16 feature buffer and/or f32 final output. 8 elems/thread.
__global__ __launch_bounds__(256) void apply_k(const unsigned short* __restrict__ raw,
                                               const float* __restrict__ S,
                                               const float* __restrict__ gamma,
                                               const float* __restrict__ beta,
                                               const unsigned short* residb,
                                               unsigned short* bfout,
                                               float* f32out) {
    int i = (blockIdx.x * 256 + threadIdx.x) * 8;
    int c0 = i & 8;                    // channels c0..c0+7
    short8 r8 = *reinterpret_cast<const short8*>(raw + i);
    float res[8] = {0, 0, 0, 0, 0, 0, 0, 0};
    if (residb) {
        short8 x8 = *reinterpret_cast<const short8*>(residb + i);
#pragma unroll
        for (int j = 0; j < 8; ++j) res[j] = bf2f((unsigned short)x8[j]);
    }
    const float inv = 1.0f / (float)N_TOT;
    float val[8];
#pragma unroll
    for (int j = 0; j < 8; ++j) {
        int c = c0 + j;
        float m   = S[c] * inv;
        float var = S[16 + c] * inv - m * m;
        float sc  = gamma[c] * rsqrtf(var + 1e-3f);
        float sh  = beta[c] - m * sc;
        val[j] = fmaxf(bf2f((unsigned short)r8[j]) * sc + sh + res[j], 0.f);
    }
    if (bfout) {
        short8 o = { (short)f2bf(val[0]), (short)f2bf(val[1]), (short)f2bf(val[2]), (short)f2bf(val[3]),
                     (short)f2bf(val[4]), (short)f2bf(val[5]), (short)f2bf(val[6]), (short)f2bf(val[7]) };
        *reinterpret_cast<short8*>(bfout + i) = o;
    }
    if (f32out) {
        f32x4 lo = { val[0], val[1], val[2], val[3] };
        f32x4 hi = { val[4], val[5], val[6], val[7] };
        *reinterpret_cast<f32x4*>(f32out + i)     = lo;
        *reinterpret_cast<f32x4*>(f32out + i + 4) = hi;
    }
}

extern "C" void kernel_launch(void* const* d_in, const int* in_sizes, int n_in,
                              void* d_out, int out_size, void* d_ws, size_t ws_size,
                              hipStream_t stream) {
    const float* vf   = (const float*)d_in[0];
    const int*   nbr  = (const int*)  d_in[1];
    const float* w_in = (const float*)d_in[2];
    const float* g_in = (const float*)d_in[3];
    const float* b_in = (const float*)d_in[4];
    const float* wbs  = (const float*)d_in[5];
    const float* gs   = (const float*)d_in[6];
    const float* bs   = (const float*)d_in[7];
    float* out = (float*)d_out;

    char* ws = (char*)d_ws;
    size_t off = 0;
    auto alloc = [&](size_t b) { char* p = ws + off; off += (b + 255) & ~(size_t)255; return p; };
    unsigned short* wfrag = (unsigned short*)alloc((size_t)5 * 14 * 64 * 8 * 2);
    unsigned short* xb    = (unsigned short*)alloc((size_t)(NELEM + 16) * 2);  // bf16 x (+zero voxel)
    unsigned short* ob    = (unsigned short*)alloc((size_t)(NELEM + 16) * 2);  // bf16 o (+zero voxel)
    unsigned short* rb    = (unsigned short*)alloc((size_t)NELEM * 2);         // bf16 raw conv out
    float*          part  = (float*)alloc((size_t)32 * CBLK * 4);
    float*          S     = (float*)alloc(32 * 4);

    const int FR = 14 * 64 * 8;  // ushorts per layer of wfrag

    wfrag_k<<<70, 64, 0, stream>>>(w_in, wbs, wfrag, xb, ob);
    cvt_k<<<3125, 256, 0, stream>>>(vf, xb);

    // L0: x0 = relu(bn(conv(vf)))                 -> xb
    conv_k<<<CBLK, 256, 0, stream>>>(xb, nbr, wfrag, rb, part);
    reduce_k<<<32, 256, 0, stream>>>(part, S);
    apply_k<<<3125, 256, 0, stream>>>(rb, S, g_in, b_in, nullptr, xb, nullptr);

    // L1: o = relu(bn(conv(x0)))                  -> ob
    conv_k<<<CBLK, 256, 0, stream>>>(xb, nbr, wfrag + FR, rb, part);
    reduce_k<<<32, 256, 0, stream>>>(part, S);
    apply_k<<<3125, 256, 0, stream>>>(rb, S, gs + 0, bs + 0, nullptr, ob, nullptr);

    // L2: x1 = relu(bn(conv(o)) + x0)             -> xb (in place resid)
    conv_k<<<CBLK, 256, 0, stream>>>(ob, nbr, wfrag + 2 * FR, rb, part);
    reduce_k<<<32, 256, 0, stream>>>(part, S);
    apply_k<<<3125, 256, 0, stream>>>(rb, S, gs + 16, bs + 16, xb, xb, nullptr);

    // L3: o = relu(bn(conv(x1)))                  -> ob
    conv_k<<<CBLK, 256, 0, stream>>>(xb, nbr, wfrag + 3 * FR, rb, part);
    reduce_k<<<32, 256, 0, stream>>>(part, S);
    apply_k<<<3125, 256, 0, stream>>>(rb, S, gs + 32, bs + 32, nullptr, ob, nullptr);

    // L4: out = relu(bn(conv(o)) + x1)            -> d_out (f32)
    conv_k<<<CBLK, 256, 0, stream>>>(ob, nbr, wfrag + 4 * FR, rb, part);
    reduce_k<<<32, 256, 0, stream>>>(part, S);
    apply_k<<<3125, 256, 0, stream>>>(rb, S, gs + 48, bs + 48, xb, nullptr, out);
}

// Round 10
// 175.525 us; speedup vs baseline: 4.6146x; 1.7606x over previous
//
#include <hip/hip_runtime.h>

#define N_TOT  400000
#define NTILE  25000        // N_TOT / 16 voxels per tile
#define NELEM  (N_TOT * 16)
#define CBLK   512          // persistent conv blocks (2 per CU)
#define GS     (CBLK * 4)   // wave grid stride (tiles)

typedef __attribute__((ext_vector_type(8))) short short8;
typedef __attribute__((ext_vector_type(4))) float f32x4;
typedef __attribute__((ext_vector_type(4))) unsigned short us4;

__device__ __forceinline__ unsigned short f2bf(float x) {
    unsigned int u = __float_as_uint(x);
    u += 0x7FFFu + ((u >> 16) & 1u);       // round-to-nearest-even
    return (unsigned short)(u >> 16);
}
__device__ __forceinline__ float bf2f(unsigned short h) {
    return __uint_as_float(((unsigned int)h) << 16);
}

// Build bf16 B-fragments for all 5 layers x 14 k-pairs, and zero the pad voxel
// (index N_TOT) in both bf16 gather buffers (invalid neighbors land there —
// all invalid lanes hit the SAME cache line, coalesced to one broadcast).
// mfma_f32_16x16x32_bf16 B layout: lane l holds B[k=8*(l>>4)+j][col=l&15].
__global__ __launch_bounds__(64) void wfrag_k(const float* __restrict__ w_in,
                                              const float* __restrict__ wbs,
                                              unsigned short* __restrict__ wfrag,
                                              unsigned short* __restrict__ xb,
                                              unsigned short* __restrict__ ob) {
    if (blockIdx.x == 0 && threadIdx.x < 8) {
        us4 z = {0, 0, 0, 0};
        unsigned short* base = (threadIdx.x < 4) ? xb : ob;
        reinterpret_cast<us4*>(base + NELEM)[threadIdx.x & 3] = z;
    }
    int b = blockIdx.x;            // L*14 + p
    int L = b / 14, p = b % 14;
    int l = threadIdx.x;
    int g = l >> 4, col = l & 15;
    int k = 2 * p + (g >> 1);
    int cib = (g & 1) * 8;
    unsigned short v[8];
#pragma unroll
    for (int j = 0; j < 8; ++j) {
        float w = 0.f;
        if (k < 27) {
            int ci = cib + j;
            w = (L == 0) ? w_in[(k * 16 + ci) * 16 + col]
                         : wbs[(((L - 1) * 27 + k) * 16 + ci) * 16 + col];
        }
        v[j] = f2bf(w);
    }
    unsigned short* dst = wfrag + (size_t)(b * 64 + l) * 8;
#pragma unroll
    for (int j = 0; j < 8; ++j) dst[j] = v[j];
}

__global__ __launch_bounds__(256) void cvt_k(const float* __restrict__ in,
                                             unsigned short* __restrict__ out) {
    int i = (blockIdx.x * 256 + threadIdx.x) * 8;
    f32x4 a = *reinterpret_cast<const f32x4*>(in + i);
    f32x4 b = *reinterpret_cast<const f32x4*>(in + i + 4);
    short8 o = { (short)f2bf(a[0]), (short)f2bf(a[1]), (short)f2bf(a[2]), (short)f2bf(a[3]),
                 (short)f2bf(b[0]), (short)f2bf(b[1]), (short)f2bf(b[2]), (short)f2bf(b[3]) };
    *reinterpret_cast<short8*>(out + i) = o;
}

// Persistent gather-MFMA conv, 3-stage decoupled pipeline per wave:
//   idx loads for tile t+2S | gathers for tile t+S | MFMA+store of tile t.
// B-fragments for all 14 pairs live in REGISTERS (loop-invariant, loaded once
// per wave) -> zero LDS traffic in the main loop. MFMA accumulator split
// even/odd to halve the dependent-chain length. Straight-line lane work only.
// Center offset (k=13) = identity (no load). Invalid -> zero voxel at N_TOT.
#define IDX(I, tt)                                                              \
  {                                                                             \
    const int vv = (tt) * 16;                                                   \
    _Pragma("unroll")                                                           \
    for (int p = 0; p < 14; ++p) {                                              \
      int k = 2 * p + ksel;                                                     \
      if (k == 13)      I[p] = vv + rc;                                         \
      else if (k < 27)  I[p] = nbr[(size_t)k * N_TOT + vv + rc];                \
      else              I[p] = -1;                                              \
    }                                                                           \
  }

#define GAT(A, I)                                                               \
  {                                                                             \
    _Pragma("unroll")                                                           \
    for (int p = 0; p < 14; ++p) {                                              \
      int ci = I[p] < 0 ? N_TOT : I[p];                                         \
      A[p] = *reinterpret_cast<const short8*>(feats + ((size_t)ci << 4) + half);\
    }                                                                           \
  }

#define CMP(A, tt)                                                              \
  {                                                                             \
    f32x4 ac0 = {0.f, 0.f, 0.f, 0.f};                                           \
    f32x4 ac1 = {0.f, 0.f, 0.f, 0.f};                                           \
    _Pragma("unroll")                                                           \
    for (int p = 0; p < 14; p += 2) {                                           \
      ac0 = __builtin_amdgcn_mfma_f32_16x16x32_bf16(A[p],     B[p],     ac0, 0, 0, 0); \
      ac1 = __builtin_amdgcn_mfma_f32_16x16x32_bf16(A[p + 1], B[p + 1], ac1, 0, 0, 0); \
    }                                                                           \
    f32x4 acc = ac0 + ac1;                                                      \
    const int vv = (tt) * 16;                                                   \
    _Pragma("unroll")                                                           \
    for (int i = 0; i < 4; ++i)                                                 \
      raw[(size_t)(vv + g * 4 + i) * 16 + rc] = f2bf(acc[i]);                   \
    s_acc += acc[0] + acc[1] + acc[2] + acc[3];                                 \
    q_acc += acc[0]*acc[0] + acc[1]*acc[1] + acc[2]*acc[2] + acc[3]*acc[3];     \
  }

__global__ __launch_bounds__(256, 2) void conv_k(const unsigned short* __restrict__ feats,
                                                 const int* __restrict__ nbr,
                                                 const unsigned short* __restrict__ wfrag,
                                                 unsigned short* __restrict__ raw,
                                                 float* __restrict__ partials) {
    __shared__ float red[128];

    const int lane = threadIdx.x & 63;
    const int wv   = threadIdx.x >> 6;
    const int g    = lane >> 4;
    const int rc   = lane & 15;        // A-row / B-col
    const int half = (g & 1) * 8;      // which 8 input channels this lane loads
    const int ksel = g >> 1;           // which offset of the pair

    // loop-invariant B-fragments: 14 x short8 = 56 VGPRs, loaded once per wave
    short8 B[14];
#pragma unroll
    for (int p = 0; p < 14; ++p)
        B[p] = *reinterpret_cast<const short8*>(wfrag + (size_t)(p * 64 + lane) * 8);

    float s_acc = 0.f, q_acc = 0.f;

    int I0[14], I1[14];
    short8 A0[14], A1[14];

    int t0 = blockIdx.x * 4 + wv;
    IDX(I0, t0);
    GAT(A0, I0);                       // one exposed stall at prologue
    int t1 = t0 + GS;
    if (t1 < NTILE) IDX(I1, t1);

    for (;;) {
        // invariant: A0 in flight for t0; I1 in flight/arrived for t1
        int t2 = t0 + 2 * GS;
        if (t2 < NTILE) IDX(I0, t2);
        if (t1 < NTILE) GAT(A1, I1);
        __builtin_amdgcn_sched_barrier(0);
        CMP(A0, t0);
        if (t1 >= NTILE) break;

        int t3 = t1 + 2 * GS;
        if (t3 < NTILE) IDX(I1, t3);
        if (t2 < NTILE) GAT(A0, I0);
        __builtin_amdgcn_sched_barrier(0);
        CMP(A1, t1);
        if (t2 >= NTILE) break;

        t0 = t2;
        t1 = t2 + GS;
    }

    // BN partials: per-channel sum & sumsq over all tiles this block touched
    s_acc += __shfl_xor(s_acc, 16);  s_acc += __shfl_xor(s_acc, 32);
    q_acc += __shfl_xor(q_acc, 16);  q_acc += __shfl_xor(q_acc, 32);
    if (lane < 16) {
        red[wv * 32 + rc]      = s_acc;
        red[wv * 32 + 16 + rc] = q_acc;
    }
    __syncthreads();
    if (threadIdx.x < 32) {
        float v = red[threadIdx.x] + red[32 + threadIdx.x] +
                  red[64 + threadIdx.x] + red[96 + threadIdx.x];
        partials[(size_t)threadIdx.x * CBLK + blockIdx.x] = v;
    }
}

__global__ __launch_bounds__(256) void reduce_k(const float* __restrict__ partials,
                                                float* __restrict__ S) {
    int c = blockIdx.x;  // 0..31 (16 sums, 16 sumsqs)
    float s = 0.f;
    for (int i = threadIdx.x; i < CBLK; i += 256) s += partials[(size_t)c * CBLK + i];
    __shared__ float red[256];
    red[threadIdx.x] = s;
    __syncthreads();
#pragma unroll
    for (int off = 128; off > 0; off >>= 1) {
        if (threadIdx.x < off) red[threadIdx.x] += red[threadIdx.x + off];
        __syncthreads();
    }
    if (threadIdx.x == 0) S[c] = red[0];
}

// BN finalize fused; reads raw bf16 conv output, optional bf16 residual,
// writes bf16 feature buffer and/or f32 final output. 8 elems/thread.
__global__ __launch_bounds__(256) void apply_k(const unsigned short* __restrict__ raw,
                                               const float* __restrict__ S,
                                               const float* __restrict__ gamma,
                                               const float* __restrict__ beta,
                                               const unsigned short* residb,
                                               unsigned short* bfout,
                                               float* f32out) {
    int i = (blockIdx.x * 256 + threadIdx.x) * 8;
    int c0 = i & 8;                    // channels c0..c0+7
    short8 r8 = *reinterpret_cast<const short8*>(raw + i);
    float res[8] = {0, 0, 0, 0, 0, 0, 0, 0};
    if (residb) {
        short8 x8 = *reinterpret_cast<const short8*>(residb + i);
#pragma unroll
        for (int j = 0; j < 8; ++j) res[j] = bf2f((unsigned short)x8[j]);
    }
    const float inv = 1.0f / (float)N_TOT;
    float val[8];
#pragma unroll
    for (int j = 0; j < 8; ++j) {
        int c = c0 + j;
        float m   = S[c] * inv;
        float var = S[16 + c] * inv - m * m;
        float sc  = gamma[c] * rsqrtf(var + 1e-3f);
        float sh  = beta[c] - m * sc;
        val[j] = fmaxf(bf2f((unsigned short)r8[j]) * sc + sh + res[j], 0.f);
    }
    if (bfout) {
        short8 o = { (short)f2bf(val[0]), (short)f2bf(val[1]), (short)f2bf(val[2]), (short)f2bf(val[3]),
                     (short)f2bf(val[4]), (short)f2bf(val[5]), (short)f2bf(val[6]), (short)f2bf(val[7]) };
        *reinterpret_cast<short8*>(bfout + i) = o;
    }
    if (f32out) {
        f32x4 lo = { val[0], val[1], val[2], val[3] };
        f32x4 hi = { val[4], val[5], val[6], val[7] };
        *reinterpret_cast<f32x4*>(f32out + i)     = lo;
        *reinterpret_cast<f32x4*>(f32out + i + 4) = hi;
    }
}

extern "C" void kernel_launch(void* const* d_in, const int* in_sizes, int n_in,
                              void* d_out, int out_size, void* d_ws, size_t ws_size,
                              hipStream_t stream) {
    const float* vf   = (const float*)d_in[0];
    const int*   nbr  = (const int*)  d_in[1];
    const float* w_in = (const float*)d_in[2];
    const float* g_in = (const float*)d_in[3];
    const float* b_in = (const float*)d_in[4];
    const float* wbs  = (const float*)d_in[5];
    const float* gs   = (const float*)d_in[6];
    const float* bs   = (const float*)d_in[7];
    float* out = (float*)d_out;

    char* ws = (char*)d_ws;
    size_t off = 0;
    auto alloc = [&](size_t b) { char* p = ws + off; off += (b + 255) & ~(size_t)255; return p; };
    unsigned short* wfrag = (unsigned short*)alloc((size_t)5 * 14 * 64 * 8 * 2);
    unsigned short* xb    = (unsigned short*)alloc((size_t)(NELEM + 16) * 2);  // bf16 x (+zero voxel)
    unsigned short* ob    = (unsigned short*)alloc((size_t)(NELEM + 16) * 2);  // bf16 o (+zero voxel)
    unsigned short* rb    = (unsigned short*)alloc((size_t)NELEM * 2);         // bf16 raw conv out
    float*          part  = (float*)alloc((size_t)32 * CBLK * 4);
    float*          S     = (float*)alloc(32 * 4);

    const int FR = 14 * 64 * 8;  // ushorts per layer of wfrag

    wfrag_k<<<70, 64, 0, stream>>>(w_in, wbs, wfrag, xb, ob);
    cvt_k<<<3125, 256, 0, stream>>>(vf, xb);

    // L0: x0 = relu(bn(conv(vf)))                 -> xb
    conv_k<<<CBLK, 256, 0, stream>>>(xb, nbr, wfrag, rb, part);
    reduce_k<<<32, 256, 0, stream>>>(part, S);
    apply_k<<<3125, 256, 0, stream>>>(rb, S, g_in, b_in, nullptr, xb, nullptr);

    // L1: o = relu(bn(conv(x0)))                  -> ob
    conv_k<<<CBLK, 256, 0, stream>>>(xb, nbr, wfrag + FR, rb, part);
    reduce_k<<<32, 256, 0, stream>>>(part, S);
    apply_k<<<3125, 256, 0, stream>>>(rb, S, gs + 0, bs + 0, nullptr, ob, nullptr);

    // L2: x1 = relu(bn(conv(o)) + x0)             -> xb (in place resid)
    conv_k<<<CBLK, 256, 0, stream>>>(ob, nbr, wfrag + 2 * FR, rb, part);
    reduce_k<<<32, 256, 0, stream>>>(part, S);
    apply_k<<<3125, 256, 0, stream>>>(rb, S, gs + 16, bs + 16, xb, xb, nullptr);

    // L3: o = relu(bn(conv(x1)))                  -> ob
    conv_k<<<CBLK, 256, 0, stream>>>(xb, nbr, wfrag + 3 * FR, rb, part);
    reduce_k<<<32, 256, 0, stream>>>(part, S);
    apply_k<<<3125, 256, 0, stream>>>(rb, S, gs + 32, bs + 32, nullptr, ob, nullptr);

    // L4: out = relu(bn(conv(o)) + x1)            -> d_out (f32)
    conv_k<<<CBLK, 256, 0, stream>>>(ob, nbr, wfrag + 4 * FR, rb, part);
    reduce_k<<<32, 256, 0, stream>>>(part, S);
    apply_k<<<3125, 256, 0, stream>>>(rb, S, gs + 48, bs + 48, xb, nullptr, out);
}